// Round 1
// baseline (372.884 us; speedup 1.0000x reference)
//
#include <hip/hip_runtime.h>
#include <hip/hip_bf16.h>

#define D_MODEL 1024
#define ATT_DIM 64
#define BATCH 8
#define SEQ 2048
#define MROWS (BATCH * SEQ)  // 16384

// ---------------------------------------------------------------------------
// K1: fused triple projection GEMM.
// out[m][e] = sum_d x[m][d] * W[e][d]   (M=16384, N=64, K=1024)
// blockIdx.y in {0,1,2} selects (q,Wq,qp), (k,Wk,kp), (v,Wv,vp).
// 64x64 output tile per block, K-chunks of 64, 4x4 register blocking.
// ---------------------------------------------------------------------------
__global__ __launch_bounds__(256) void proj3_kernel(
    const float* __restrict__ q, const float* __restrict__ k,
    const float* __restrict__ v, const float* __restrict__ Wq,
    const float* __restrict__ Wk, const float* __restrict__ Wv,
    float* __restrict__ qp, float* __restrict__ kp, float* __restrict__ vp)
{
    const float* x;
    const float* W;
    float* out;
    if (blockIdx.y == 0)      { x = q; W = Wq; out = qp; }
    else if (blockIdx.y == 1) { x = k; W = Wk; out = kp; }
    else                      { x = v; W = Wv; out = vp; }

    __shared__ float xs[64][65];   // xs[row][kk]
    __shared__ float wsh[64][65];  // wsh[kk][e]

    const int tid = threadIdx.x;
    const int ty = tid >> 4;   // 0..15
    const int tx = tid & 15;   // 0..15
    const int m0 = blockIdx.x * 64;

    float acc[4][4] = {};

    for (int kt = 0; kt < D_MODEL; kt += 64) {
        // stage x tile: 64 rows x 64 cols
        {
            const int r = tid >> 4;
            const int c = (tid & 15) * 4;
            #pragma unroll
            for (int rr = 0; rr < 4; ++rr) {
                const float4 t = *reinterpret_cast<const float4*>(
                    &x[(size_t)(m0 + r + rr * 16) * D_MODEL + kt + c]);
                xs[r + rr * 16][c + 0] = t.x;
                xs[r + rr * 16][c + 1] = t.y;
                xs[r + rr * 16][c + 2] = t.z;
                xs[r + rr * 16][c + 3] = t.w;
            }
        }
        // stage W tile transposed: wsh[kk][e] = W[e][kt+kk]
        {
            const int e = tid >> 4;
            const int c = (tid & 15) * 4;
            #pragma unroll
            for (int rr = 0; rr < 4; ++rr) {
                const float4 t = *reinterpret_cast<const float4*>(
                    &W[(size_t)(e + rr * 16) * D_MODEL + kt + c]);
                wsh[c + 0][e + rr * 16] = t.x;
                wsh[c + 1][e + rr * 16] = t.y;
                wsh[c + 2][e + rr * 16] = t.z;
                wsh[c + 3][e + rr * 16] = t.w;
            }
        }
        __syncthreads();
        #pragma unroll
        for (int kk = 0; kk < 64; ++kk) {
            float a[4], b[4];
            #pragma unroll
            for (int i = 0; i < 4; ++i) a[i] = xs[ty * 4 + i][kk];
            #pragma unroll
            for (int j = 0; j < 4; ++j) b[j] = wsh[kk][tx * 4 + j];
            #pragma unroll
            for (int i = 0; i < 4; ++i)
                #pragma unroll
                for (int j = 0; j < 4; ++j) acc[i][j] += a[i] * b[j];
        }
        __syncthreads();
    }

    #pragma unroll
    for (int i = 0; i < 4; ++i) {
        const size_t m = (size_t)(m0 + ty * 4 + i);
        #pragma unroll
        for (int j = 0; j < 4; ++j)
            out[m * ATT_DIM + tx * 4 + j] = acc[i][j];
    }
}

// ---------------------------------------------------------------------------
// K2: scores[b][qi][ki] = dot(qp[b][qi], kp[b][ki]) / ATT_DIM
// Written (pre-softmax) into the probs output buffer.
// 64x64 tile per block, K=64 (single chunk).
// ---------------------------------------------------------------------------
__global__ __launch_bounds__(256) void scores_kernel(
    const float* __restrict__ qp, const float* __restrict__ kp,
    float* __restrict__ probs)
{
    __shared__ float qs[64][65];   // qs[qi][e]
    __shared__ float kst[64][65];  // kst[e][ki]

    const int b = blockIdx.z;
    const int q0 = blockIdx.y * 64;
    const int k0 = blockIdx.x * 64;
    const float* qpb = qp + (size_t)b * SEQ * ATT_DIM;
    const float* kpb = kp + (size_t)b * SEQ * ATT_DIM;

    const int tid = threadIdx.x;
    const int ty = tid >> 4;
    const int tx = tid & 15;

    {
        const int r = tid >> 4;
        const int c = (tid & 15) * 4;
        #pragma unroll
        for (int rr = 0; rr < 4; ++rr) {
            const float4 t = *reinterpret_cast<const float4*>(
                &qpb[(size_t)(q0 + r + rr * 16) * ATT_DIM + c]);
            qs[r + rr * 16][c + 0] = t.x;
            qs[r + rr * 16][c + 1] = t.y;
            qs[r + rr * 16][c + 2] = t.z;
            qs[r + rr * 16][c + 3] = t.w;
        }
        #pragma unroll
        for (int rr = 0; rr < 4; ++rr) {
            const float4 t = *reinterpret_cast<const float4*>(
                &kpb[(size_t)(k0 + r + rr * 16) * ATT_DIM + c]);
            kst[c + 0][r + rr * 16] = t.x;
            kst[c + 1][r + rr * 16] = t.y;
            kst[c + 2][r + rr * 16] = t.z;
            kst[c + 3][r + rr * 16] = t.w;
        }
    }
    __syncthreads();

    float acc[4][4] = {};
    #pragma unroll
    for (int e = 0; e < 64; ++e) {
        float a[4], bb[4];
        #pragma unroll
        for (int i = 0; i < 4; ++i) a[i] = qs[ty * 4 + i][e];
        #pragma unroll
        for (int j = 0; j < 4; ++j) bb[j] = kst[e][tx * 4 + j];
        #pragma unroll
        for (int i = 0; i < 4; ++i)
            #pragma unroll
            for (int j = 0; j < 4; ++j) acc[i][j] += a[i] * bb[j];
    }

    const float inv = 1.0f / (float)ATT_DIM;
    float* pb = probs + (size_t)b * SEQ * SEQ;
    #pragma unroll
    for (int i = 0; i < 4; ++i) {
        const size_t row = (size_t)(q0 + ty * 4 + i);
        #pragma unroll
        for (int j = 0; j < 4; ++j)
            pb[row * SEQ + k0 + tx * 4 + j] = acc[i][j] * inv;
    }
}

// ---------------------------------------------------------------------------
// K3: in-place row softmax over probs rows (length SEQ=2048).
// One block (256 threads) per row; 8 elements per thread (2x float4).
// ---------------------------------------------------------------------------
__global__ __launch_bounds__(256) void softmax_kernel(float* __restrict__ probs)
{
    __shared__ float red[8];
    const size_t row = blockIdx.x;
    float* p = probs + row * (size_t)SEQ;
    const int tid = threadIdx.x;

    float4 v0 = reinterpret_cast<float4*>(p)[tid];
    float4 v1 = reinterpret_cast<float4*>(p)[tid + 256];

    // --- max reduce ---
    float m = fmaxf(fmaxf(fmaxf(v0.x, v0.y), fmaxf(v0.z, v0.w)),
                    fmaxf(fmaxf(v1.x, v1.y), fmaxf(v1.z, v1.w)));
    #pragma unroll
    for (int off = 32; off > 0; off >>= 1)
        m = fmaxf(m, __shfl_xor(m, off));
    if ((tid & 63) == 0) red[tid >> 6] = m;
    __syncthreads();
    if (tid == 0) {
        float t = fmaxf(fmaxf(red[0], red[1]), fmaxf(red[2], red[3]));
        red[4] = t;
    }
    __syncthreads();
    m = red[4];

    // --- exp + sum ---
    v0.x = __expf(v0.x - m); v0.y = __expf(v0.y - m);
    v0.z = __expf(v0.z - m); v0.w = __expf(v0.w - m);
    v1.x = __expf(v1.x - m); v1.y = __expf(v1.y - m);
    v1.z = __expf(v1.z - m); v1.w = __expf(v1.w - m);
    float s = v0.x + v0.y + v0.z + v0.w + v1.x + v1.y + v1.z + v1.w;
    #pragma unroll
    for (int off = 32; off > 0; off >>= 1)
        s += __shfl_xor(s, off);
    if ((tid & 63) == 0) red[tid >> 6] = s;
    __syncthreads();
    if (tid == 0) red[5] = red[0] + red[1] + red[2] + red[3];
    __syncthreads();
    const float scale = 1.0f / red[5];

    v0.x *= scale; v0.y *= scale; v0.z *= scale; v0.w *= scale;
    v1.x *= scale; v1.y *= scale; v1.z *= scale; v1.w *= scale;
    reinterpret_cast<float4*>(p)[tid] = v0;
    reinterpret_cast<float4*>(p)[tid + 256] = v1;
}

// ---------------------------------------------------------------------------
// K4: att[b][qi][e] = sum_k probs[b][qi][k] * vp[b][k][e]
// M=2048, N=64(full), K=2048 per batch. 64-row tile per block.
// ---------------------------------------------------------------------------
__global__ __launch_bounds__(256) void att_kernel(
    const float* __restrict__ probs, const float* __restrict__ vp,
    float* __restrict__ att)
{
    __shared__ float ps[64][65];  // ps[qi][kk]
    __shared__ float vs[64][65];  // vs[kk][e]

    const int b = blockIdx.z;
    const int q0 = blockIdx.x * 64;
    const float* pb = probs + (size_t)b * SEQ * SEQ;
    const float* vpb = vp + (size_t)b * SEQ * ATT_DIM;

    const int tid = threadIdx.x;
    const int ty = tid >> 4;
    const int tx = tid & 15;

    float acc[4][4] = {};

    for (int kt = 0; kt < SEQ; kt += 64) {
        const int r = tid >> 4;
        const int c = (tid & 15) * 4;
        #pragma unroll
        for (int rr = 0; rr < 4; ++rr) {
            const float4 t = *reinterpret_cast<const float4*>(
                &pb[(size_t)(q0 + r + rr * 16) * SEQ + kt + c]);
            ps[r + rr * 16][c + 0] = t.x;
            ps[r + rr * 16][c + 1] = t.y;
            ps[r + rr * 16][c + 2] = t.z;
            ps[r + rr * 16][c + 3] = t.w;
        }
        #pragma unroll
        for (int rr = 0; rr < 4; ++rr) {
            const float4 t = *reinterpret_cast<const float4*>(
                &vpb[(size_t)(kt + r + rr * 16) * ATT_DIM + c]);
            vs[r + rr * 16][c + 0] = t.x;
            vs[r + rr * 16][c + 1] = t.y;
            vs[r + rr * 16][c + 2] = t.z;
            vs[r + rr * 16][c + 3] = t.w;
        }
        __syncthreads();
        #pragma unroll
        for (int kk = 0; kk < 64; ++kk) {
            float a[4], bb[4];
            #pragma unroll
            for (int i = 0; i < 4; ++i) a[i] = ps[ty * 4 + i][kk];
            #pragma unroll
            for (int j = 0; j < 4; ++j) bb[j] = vs[kk][tx * 4 + j];
            #pragma unroll
            for (int i = 0; i < 4; ++i)
                #pragma unroll
                for (int j = 0; j < 4; ++j) acc[i][j] += a[i] * bb[j];
        }
        __syncthreads();
    }

    float* ab = att + (size_t)b * SEQ * ATT_DIM;
    #pragma unroll
    for (int i = 0; i < 4; ++i) {
        const size_t row = (size_t)(q0 + ty * 4 + i);
        #pragma unroll
        for (int j = 0; j < 4; ++j)
            ab[row * ATT_DIM + tx * 4 + j] = acc[i][j];
    }
}

// ---------------------------------------------------------------------------
extern "C" void kernel_launch(void* const* d_in, const int* in_sizes, int n_in,
                              void* d_out, int out_size, void* d_ws, size_t ws_size,
                              hipStream_t stream)
{
    const float* q  = (const float*)d_in[0];
    const float* k  = (const float*)d_in[1];
    const float* v  = (const float*)d_in[2];
    const float* Wq = (const float*)d_in[3];
    const float* Wk = (const float*)d_in[4];
    const float* Wv = (const float*)d_in[5];

    float* att   = (float*)d_out;                                // [B,S,64]
    float* probs = att + (size_t)BATCH * SEQ * ATT_DIM;          // [B,S,S]

    float* qp = (float*)d_ws;                                    // [B,S,64]
    float* kp = qp + (size_t)BATCH * SEQ * ATT_DIM;
    float* vp = kp + (size_t)BATCH * SEQ * ATT_DIM;

    proj3_kernel<<<dim3(MROWS / 64, 3), 256, 0, stream>>>(
        q, k, v, Wq, Wk, Wv, qp, kp, vp);

    scores_kernel<<<dim3(SEQ / 64, SEQ / 64, BATCH), 256, 0, stream>>>(
        qp, kp, probs);

    softmax_kernel<<<dim3(MROWS), 256, 0, stream>>>(probs);

    att_kernel<<<dim3(SEQ / 64, 1, BATCH), 256, 0, stream>>>(probs, vp, att);
}

// Round 2
// 178.430 us; speedup vs baseline: 2.0898x; 2.0898x over previous
//
#include <hip/hip_runtime.h>
#include <hip/hip_bf16.h>

#define D_MODEL 1024
#define ATT_DIM 64
#define BATCH 8
#define SEQ 2048
#define MROWS (BATCH * SEQ)  // 16384

typedef short bf16x8 __attribute__((ext_vector_type(8)));
typedef float f32x4 __attribute__((ext_vector_type(4)));

#define MFMA16(a, b, c) __builtin_amdgcn_mfma_f32_16x16x32_bf16((a), (b), (c), 0, 0, 0)

__device__ inline short f2bf(float f) {
    union { __hip_bfloat16 h; short s; } u;
    u.h = __float2bfloat16(f);  // RNE
    return u.s;
}

// ---------------------------------------------------------------------------
// K0: convert Wq,Wk,Wv fp32 -> bf16 workspace [3][64][1024].
// Wq is pre-scaled by 1/64 (exact power of two) so scores = MFMA output.
// ---------------------------------------------------------------------------
__global__ __launch_bounds__(256) void wcvt_kernel(
    const float* __restrict__ Wq, const float* __restrict__ Wk,
    const float* __restrict__ Wv, short* __restrict__ Wbf)
{
    const int idx = blockIdx.x * 256 + threadIdx.x;   // 24576 threads
    const int per = ATT_DIM * D_MODEL;                // 65536
    const int base = idx * 8;
    const int mi = base / per;
    const int off = base - mi * per;
    const float* src = (mi == 0) ? Wq : (mi == 1 ? Wk : Wv);
    const float sc = (mi == 0) ? (1.0f / 64.0f) : 1.0f;
    const float4 a = *reinterpret_cast<const float4*>(src + off);
    const float4 b = *reinterpret_cast<const float4*>(src + off + 4);
    bf16x8 r;
    r[0] = f2bf(a.x * sc); r[1] = f2bf(a.y * sc);
    r[2] = f2bf(a.z * sc); r[3] = f2bf(a.w * sc);
    r[4] = f2bf(b.x * sc); r[5] = f2bf(b.y * sc);
    r[6] = f2bf(b.z * sc); r[7] = f2bf(b.w * sc);
    *reinterpret_cast<bf16x8*>(Wbf + base) = r;
}

// ---------------------------------------------------------------------------
// K1: projections via MFMA, fragments straight from global (no LDS).
// out[m][e] = sum_d x[m][d]*W[e][d].  Block=4 waves, each wave 16 rows.
// blockIdx.y selects matrix; V output is stored TRANSPOSED per batch:
// vpT[b][e][s] (bf16) so the PV MFMA A-operand reads contiguously.
// ---------------------------------------------------------------------------
__global__ __launch_bounds__(256) void proj_mfma_kernel(
    const float* __restrict__ q, const float* __restrict__ k,
    const float* __restrict__ v, const short* __restrict__ Wbf,
    short* __restrict__ qp, short* __restrict__ kp, short* __restrict__ vpT)
{
    const int mat = blockIdx.y;  // 0:q 1:k 2:v
    const float* x = (mat == 0) ? q : (mat == 1 ? k : v);
    const short* W = Wbf + mat * ATT_DIM * D_MODEL;

    const int tid = threadIdx.x;
    const int w = tid >> 6;
    const int l = tid & 63;
    const int lr = l & 15;   // row (A) / col (B,D) within fragment
    const int g = l >> 4;    // k-group

    const int m0 = blockIdx.x * 64 + w * 16;
    const long arow = (long)(m0 + lr) * D_MODEL;

    f32x4 acc[4] = {};

    for (int kt = 0; kt < D_MODEL; kt += 32) {
        const float4 a0 = *reinterpret_cast<const float4*>(x + arow + kt + g * 8);
        const float4 a1 = *reinterpret_cast<const float4*>(x + arow + kt + g * 8 + 4);
        bf16x8 af;
        af[0] = f2bf(a0.x); af[1] = f2bf(a0.y); af[2] = f2bf(a0.z); af[3] = f2bf(a0.w);
        af[4] = f2bf(a1.x); af[5] = f2bf(a1.y); af[6] = f2bf(a1.z); af[7] = f2bf(a1.w);
        #pragma unroll
        for (int ef = 0; ef < 4; ++ef) {
            const bf16x8 bf_ = *reinterpret_cast<const bf16x8*>(
                W + (ef * 16 + lr) * D_MODEL + kt + g * 8);
            acc[ef] = MFMA16(af, bf_, acc[ef]);
        }
    }

    // D layout: row=(l>>4)*4+j, col=lr (within each 16-col fragment ef)
    if (mat < 2) {
        short* out = (mat == 0) ? qp : kp;
        #pragma unroll
        for (int ef = 0; ef < 4; ++ef)
            #pragma unroll
            for (int j = 0; j < 4; ++j)
                out[(long)(m0 + g * 4 + j) * ATT_DIM + ef * 16 + lr] = f2bf(acc[ef][j]);
    } else {
        const int b = m0 / SEQ;
        const int s0 = m0 - b * SEQ;
        #pragma unroll
        for (int ef = 0; ef < 4; ++ef)
            #pragma unroll
            for (int j = 0; j < 4; ++j)
                vpT[((long)b * ATT_DIM + ef * 16 + lr) * SEQ + s0 + g * 4 + j] =
                    f2bf(acc[ef][j]);
    }
}

// ---------------------------------------------------------------------------
// K2: fused scores+softmax+PV.  One block = one 16-row Q group of one batch.
// 4 waves split the k-range (512 each).  Pass A: QK^T (MFMA) + online (m,l).
// Merge m,l across lanes then waves.  Pass B: recompute QK^T, write
// normalized probs (fp32, coalesced 64B segments), P->bf16 via per-wave LDS
// transpose, accumulate O^T = V^T * P via MFMA.  Epilogue: merge O across
// waves in LDS, coalesced float4 att store.
// ---------------------------------------------------------------------------
__global__ __launch_bounds__(256) void attn_kernel(
    const short* __restrict__ qp, const short* __restrict__ kp,
    const short* __restrict__ vpT, float* __restrict__ probs,
    float* __restrict__ att)
{
    __shared__ short lds_p[4][16][40];   // [wave][q][k-local], stride 80B
    __shared__ float lds_m[4][16];
    __shared__ float lds_l[4][16];
    __shared__ float lds_o[4][64][17];   // [wave][e][q]

    const int tid = threadIdx.x;
    const int w = tid >> 6;
    const int l = tid & 63;
    const int lr = l & 15;
    const int g = l >> 4;

    const int b = blockIdx.y;
    const int q0 = blockIdx.x * 16;

    const short* qpb = qp + ((long)b * SEQ + q0) * ATT_DIM;
    const short* kpb = kp + (long)b * SEQ * ATT_DIM;
    const short* vTb = vpT + (long)b * ATT_DIM * SEQ;

    // Q fragments (A operand), hoisted: rows q0..q0+15, d split 0-31 / 32-63
    const bf16x8 qa0 = *reinterpret_cast<const bf16x8*>(qpb + lr * ATT_DIM + g * 8);
    const bf16x8 qa1 = *reinterpret_cast<const bf16x8*>(qpb + lr * ATT_DIM + 32 + g * 8);

    const int kbeg = w * (SEQ / 4);
    const int kend = kbeg + (SEQ / 4);

    float m[4] = {-1e30f, -1e30f, -1e30f, -1e30f};
    float lsum[4] = {0.f, 0.f, 0.f, 0.f};

    // ---------------- pass A: online max / sum-exp ----------------
    for (int k0 = kbeg; k0 < kend; k0 += 32) {
        const bf16x8 kb00 = *reinterpret_cast<const bf16x8*>(kpb + (long)(k0 + lr) * ATT_DIM + g * 8);
        const bf16x8 kb01 = *reinterpret_cast<const bf16x8*>(kpb + (long)(k0 + lr) * ATT_DIM + 32 + g * 8);
        const bf16x8 kb10 = *reinterpret_cast<const bf16x8*>(kpb + (long)(k0 + 16 + lr) * ATT_DIM + g * 8);
        const bf16x8 kb11 = *reinterpret_cast<const bf16x8*>(kpb + (long)(k0 + 16 + lr) * ATT_DIM + 32 + g * 8);
        f32x4 s0 = {}, s1 = {};
        s0 = MFMA16(qa0, kb00, s0);
        s0 = MFMA16(qa1, kb01, s0);
        s1 = MFMA16(qa0, kb10, s1);
        s1 = MFMA16(qa1, kb11, s1);
        #pragma unroll
        for (int j = 0; j < 4; ++j) {
            const float a = s0[j], c = s1[j];
            const float mx = fmaxf(fmaxf(a, c), m[j]);
            lsum[j] = lsum[j] * __expf(m[j] - mx) + __expf(a - mx) + __expf(c - mx);
            m[j] = mx;
        }
    }

    // cross-lane merge (16 lanes of same k-column set share each q-row group)
    #pragma unroll
    for (int j = 0; j < 4; ++j) {
        float mj = m[j];
        #pragma unroll
        for (int off = 1; off < 16; off <<= 1) mj = fmaxf(mj, __shfl_xor(mj, off));
        float lj = lsum[j] * __expf(m[j] - mj);
        #pragma unroll
        for (int off = 1; off < 16; off <<= 1) lj += __shfl_xor(lj, off);
        m[j] = mj; lsum[j] = lj;
    }
    if (lr == 0) {
        #pragma unroll
        for (int j = 0; j < 4; ++j) {
            lds_m[w][g * 4 + j] = m[j];
            lds_l[w][g * 4 + j] = lsum[j];
        }
    }
    __syncthreads();

    float invl[4];
    #pragma unroll
    for (int j = 0; j < 4; ++j) {
        const int qr = g * 4 + j;
        const float mf = fmaxf(fmaxf(lds_m[0][qr], lds_m[1][qr]),
                               fmaxf(lds_m[2][qr], lds_m[3][qr]));
        const float lf = lds_l[0][qr] * __expf(lds_m[0][qr] - mf) +
                         lds_l[1][qr] * __expf(lds_m[1][qr] - mf) +
                         lds_l[2][qr] * __expf(lds_m[2][qr] - mf) +
                         lds_l[3][qr] * __expf(lds_m[3][qr] - mf);
        m[j] = mf;
        invl[j] = 1.0f / lf;
    }

    // ---------------- pass B: recompute, write probs, accumulate O ----------
    f32x4 accO[4] = {};
    float* pbase = probs + ((long)b * SEQ + q0) * SEQ;

    for (int k0 = kbeg; k0 < kend; k0 += 32) {
        const bf16x8 kb00 = *reinterpret_cast<const bf16x8*>(kpb + (long)(k0 + lr) * ATT_DIM + g * 8);
        const bf16x8 kb01 = *reinterpret_cast<const bf16x8*>(kpb + (long)(k0 + lr) * ATT_DIM + 32 + g * 8);
        const bf16x8 kb10 = *reinterpret_cast<const bf16x8*>(kpb + (long)(k0 + 16 + lr) * ATT_DIM + g * 8);
        const bf16x8 kb11 = *reinterpret_cast<const bf16x8*>(kpb + (long)(k0 + 16 + lr) * ATT_DIM + 32 + g * 8);
        f32x4 s0 = {}, s1 = {};
        s0 = MFMA16(qa0, kb00, s0);
        s0 = MFMA16(qa1, kb01, s0);
        s1 = MFMA16(qa0, kb10, s1);
        s1 = MFMA16(qa1, kb11, s1);

        #pragma unroll
        for (int j = 0; j < 4; ++j) {
            const int qr = g * 4 + j;
            const float p0 = __expf(s0[j] - m[j]) * invl[j];
            const float p1 = __expf(s1[j] - m[j]) * invl[j];
            pbase[(long)qr * SEQ + k0 + lr] = p0;
            pbase[(long)qr * SEQ + k0 + 16 + lr] = p1;
            lds_p[w][qr][lr] = f2bf(p0);
            lds_p[w][qr][16 + lr] = f2bf(p1);
        }
        // B operand for PV: b[i] = P[k0+8g+i][q=lr]
        const bf16x8 pb = *reinterpret_cast<const bf16x8*>(&lds_p[w][lr][g * 8]);
        #pragma unroll
        for (int ef = 0; ef < 4; ++ef) {
            const bf16x8 va = *reinterpret_cast<const bf16x8*>(
                vTb + (long)(ef * 16 + lr) * SEQ + k0 + g * 8);
            accO[ef] = MFMA16(va, pb, accO[ef]);
        }
    }

    // ---------------- merge O across waves, store att ----------------
    #pragma unroll
    for (int ef = 0; ef < 4; ++ef)
        #pragma unroll
        for (int j = 0; j < 4; ++j)
            lds_o[w][ef * 16 + g * 4 + j][lr] = accO[ef][j];
    __syncthreads();

    {
        const int qr = tid >> 4;          // 0..15
        const int e4 = (tid & 15) * 4;    // 0..60
        float4 o;
        o.x = lds_o[0][e4 + 0][qr] + lds_o[1][e4 + 0][qr] + lds_o[2][e4 + 0][qr] + lds_o[3][e4 + 0][qr];
        o.y = lds_o[0][e4 + 1][qr] + lds_o[1][e4 + 1][qr] + lds_o[2][e4 + 1][qr] + lds_o[3][e4 + 1][qr];
        o.z = lds_o[0][e4 + 2][qr] + lds_o[1][e4 + 2][qr] + lds_o[2][e4 + 2][qr] + lds_o[3][e4 + 2][qr];
        o.w = lds_o[0][e4 + 3][qr] + lds_o[1][e4 + 3][qr] + lds_o[2][e4 + 3][qr] + lds_o[3][e4 + 3][qr];
        *reinterpret_cast<float4*>(att + ((long)b * SEQ + q0 + qr) * ATT_DIM + e4) = o;
    }
}

// ---------------------------------------------------------------------------
extern "C" void kernel_launch(void* const* d_in, const int* in_sizes, int n_in,
                              void* d_out, int out_size, void* d_ws, size_t ws_size,
                              hipStream_t stream)
{
    const float* q  = (const float*)d_in[0];
    const float* k  = (const float*)d_in[1];
    const float* v  = (const float*)d_in[2];
    const float* Wq = (const float*)d_in[3];
    const float* Wk = (const float*)d_in[4];
    const float* Wv = (const float*)d_in[5];

    float* att   = (float*)d_out;                        // [B,S,64]
    float* probs = att + (size_t)BATCH * SEQ * ATT_DIM;  // [B,S,S]

    short* qp  = (short*)d_ws;                    // [B*S,64] bf16 (pre-scaled 1/64)
    short* kp  = qp + (size_t)MROWS * ATT_DIM;    // [B*S,64] bf16
    short* vpT = kp + (size_t)MROWS * ATT_DIM;    // [B][64][S] bf16
    short* Wbf = vpT + (size_t)MROWS * ATT_DIM;   // [3][64][1024] bf16

    wcvt_kernel<<<dim3(96), 256, 0, stream>>>(Wq, Wk, Wv, Wbf);

    proj_mfma_kernel<<<dim3(MROWS / 64, 3), 256, 0, stream>>>(
        q, k, v, Wbf, qp, kp, vpT);

    attn_kernel<<<dim3(SEQ / 16, BATCH), 256, 0, stream>>>(
        qp, kp, vpT, probs, att);
}

// Round 3
// 170.802 us; speedup vs baseline: 2.1831x; 1.0447x over previous
//
#include <hip/hip_runtime.h>
#include <hip/hip_bf16.h>

#define D_MODEL 1024
#define ATT_DIM 64
#define BATCH 8
#define SEQ 2048
#define MROWS (BATCH * SEQ)  // 16384

typedef short bf16x8 __attribute__((ext_vector_type(8)));
typedef float f32x4 __attribute__((ext_vector_type(4)));

#define MFMA16(a, b, c) __builtin_amdgcn_mfma_f32_16x16x32_bf16((a), (b), (c), 0, 0, 0)

__device__ inline short f2bf(float f) {
    union { __hip_bfloat16 h; short s; } u;
    u.h = __float2bfloat16(f);  // RNE
    return u.s;
}

// ---------------------------------------------------------------------------
// K0: convert Wq,Wk,Wv fp32 -> bf16 workspace [3][64][1024].
// Wq pre-scaled by 1/64 (exact pow2) so MFMA output == scores.
// ---------------------------------------------------------------------------
__global__ __launch_bounds__(256) void wcvt_kernel(
    const float* __restrict__ Wq, const float* __restrict__ Wk,
    const float* __restrict__ Wv, short* __restrict__ Wbf)
{
    const int idx = blockIdx.x * 256 + threadIdx.x;   // 24576 threads
    const int per = ATT_DIM * D_MODEL;                // 65536
    const int base = idx * 8;
    const int mi = base / per;
    const int off = base - mi * per;
    const float* src = (mi == 0) ? Wq : (mi == 1 ? Wk : Wv);
    const float sc = (mi == 0) ? (1.0f / 64.0f) : 1.0f;
    const float4 a = *reinterpret_cast<const float4*>(src + off);
    const float4 b = *reinterpret_cast<const float4*>(src + off + 4);
    bf16x8 r;
    r[0] = f2bf(a.x * sc); r[1] = f2bf(a.y * sc);
    r[2] = f2bf(a.z * sc); r[3] = f2bf(a.w * sc);
    r[4] = f2bf(b.x * sc); r[5] = f2bf(b.y * sc);
    r[6] = f2bf(b.z * sc); r[7] = f2bf(b.w * sc);
    *reinterpret_cast<bf16x8*>(Wbf + base) = r;
}

// ---------------------------------------------------------------------------
// K1: projections via MFMA, split-K x2 for occupancy.
// Block = 256 thr = 4 waves: wave (wr, kh): rows m0+16*wr, K-half kh.
// Grid = (MROWS/32, 3): 1536 blocks -> ~24 waves/CU.
// Each 128-col chunk issues all 8 A-loads up front (latency batching).
// kh==1 waves dump partial acc to LDS; kh==0 waves add + store.
// V output stored transposed: vpT[b][e][s] bf16.
// ---------------------------------------------------------------------------
__global__ __launch_bounds__(256) void proj_mfma_kernel(
    const float* __restrict__ q, const float* __restrict__ k,
    const float* __restrict__ v, const short* __restrict__ Wbf,
    short* __restrict__ qp, short* __restrict__ kp, short* __restrict__ vpT)
{
    const int mat = blockIdx.y;  // 0:q 1:k 2:v
    const float* x = (mat == 0) ? q : (mat == 1 ? k : v);
    const short* W = Wbf + mat * ATT_DIM * D_MODEL;

    __shared__ float red[2][16][65];

    const int tid = threadIdx.x;
    const int w = tid >> 6;
    const int l = tid & 63;
    const int lr = l & 15;
    const int g = l >> 4;
    const int wr = w & 1;   // row half
    const int kh = w >> 1;  // K half

    const int m0 = blockIdx.x * 32 + wr * 16;
    const long arow = (long)(m0 + lr) * D_MODEL;
    const int kbase = kh * 512;

    f32x4 acc[4] = {};

    for (int kt = 0; kt < 512; kt += 128) {
        float4 abuf[8];
        #pragma unroll
        for (int c = 0; c < 4; ++c) {
            abuf[c * 2]     = *reinterpret_cast<const float4*>(x + arow + kbase + kt + c * 32 + g * 8);
            abuf[c * 2 + 1] = *reinterpret_cast<const float4*>(x + arow + kbase + kt + c * 32 + g * 8 + 4);
        }
        #pragma unroll
        for (int c = 0; c < 4; ++c) {
            bf16x8 af;
            af[0] = f2bf(abuf[c * 2].x);     af[1] = f2bf(abuf[c * 2].y);
            af[2] = f2bf(abuf[c * 2].z);     af[3] = f2bf(abuf[c * 2].w);
            af[4] = f2bf(abuf[c * 2 + 1].x); af[5] = f2bf(abuf[c * 2 + 1].y);
            af[6] = f2bf(abuf[c * 2 + 1].z); af[7] = f2bf(abuf[c * 2 + 1].w);
            #pragma unroll
            for (int ef = 0; ef < 4; ++ef) {
                const bf16x8 bf_ = *reinterpret_cast<const bf16x8*>(
                    W + (ef * 16 + lr) * D_MODEL + kbase + kt + c * 32 + g * 8);
                acc[ef] = MFMA16(af, bf_, acc[ef]);
            }
        }
    }

    // merge K halves
    if (kh == 1) {
        #pragma unroll
        for (int ef = 0; ef < 4; ++ef)
            #pragma unroll
            for (int j = 0; j < 4; ++j)
                red[wr][g * 4 + j][ef * 16 + lr] = acc[ef][j];
    }
    __syncthreads();
    if (kh == 1) return;

    #pragma unroll
    for (int ef = 0; ef < 4; ++ef)
        #pragma unroll
        for (int j = 0; j < 4; ++j)
            acc[ef][j] += red[wr][g * 4 + j][ef * 16 + lr];

    // D layout: row = g*4+j, col = lr (within each 16-col tile ef)
    if (mat < 2) {
        short* out = (mat == 0) ? qp : kp;
        #pragma unroll
        for (int ef = 0; ef < 4; ++ef)
            #pragma unroll
            for (int j = 0; j < 4; ++j)
                out[(long)(m0 + g * 4 + j) * ATT_DIM + ef * 16 + lr] = f2bf(acc[ef][j]);
    } else {
        const int b = m0 / SEQ;
        const int s0 = m0 - b * SEQ;
        #pragma unroll
        for (int ef = 0; ef < 4; ++ef)
            #pragma unroll
            for (int j = 0; j < 4; ++j)
                vpT[((long)b * ATT_DIM + ef * 16 + lr) * SEQ + s0 + g * 4 + j] =
                    f2bf(acc[ef][j]);
    }
}

// ---------------------------------------------------------------------------
// K2: fused scores+softmax+PV with register-resident score panel.
// Block = 512 thr = 8 waves; QBLK=16; wave w owns k-range [w*256,(w+1)*256).
// Pass A: pure QK^T MFMA into s[8][2] (64 VGPR). Softmax: reg tree-max ->
// shfl -> LDS cross-wave max -> exp once per score (in place) -> reg sum ->
// shfl -> LDS cross-wave sum. Pass B: write normalized probs from regs,
// PV via per-wave LDS transpose, MFMA accumulate. O merged across waves in
// LDS (union-overlaid with pass-A/B scratch).
// ---------------------------------------------------------------------------
union AttnSmem {
    struct {
        short p[8][16][40];   // per-wave P transpose tile (80B row, 16B aligned)
        float m[8][16];
        float l[8][16];
    } a;
    float o[8][64][17];       // per-wave O^T for final merge
};

__global__ __launch_bounds__(512) void attn_kernel(
    const short* __restrict__ qp, const short* __restrict__ kp,
    const short* __restrict__ vpT, float* __restrict__ probs,
    float* __restrict__ att)
{
    __shared__ AttnSmem lds;

    const int tid = threadIdx.x;
    const int w = tid >> 6;    // 0..7
    const int l = tid & 63;
    const int lr = l & 15;
    const int g = l >> 4;

    const int b = blockIdx.y;
    const int q0 = blockIdx.x * 16;

    const short* qpb = qp + ((long)b * SEQ + q0) * ATT_DIM;
    const short* kpb = kp + (long)b * SEQ * ATT_DIM;
    const short* vTb = vpT + (long)b * ATT_DIM * SEQ;

    const bf16x8 qa0 = *reinterpret_cast<const bf16x8*>(qpb + lr * ATT_DIM + g * 8);
    const bf16x8 qa1 = *reinterpret_cast<const bf16x8*>(qpb + lr * ATT_DIM + 32 + g * 8);

    const int kbeg = w * 256;

    // ---------------- pass A: QK^T only (fully pipelineable) ----------------
    f32x4 s[8][2];
    #pragma unroll
    for (int ch = 0; ch < 8; ++ch) {
        const short* kb = kpb + (long)(kbeg + ch * 32) * ATT_DIM;
        const bf16x8 kb00 = *reinterpret_cast<const bf16x8*>(kb + lr * ATT_DIM + g * 8);
        const bf16x8 kb01 = *reinterpret_cast<const bf16x8*>(kb + lr * ATT_DIM + 32 + g * 8);
        const bf16x8 kb10 = *reinterpret_cast<const bf16x8*>(kb + (16 + lr) * ATT_DIM + g * 8);
        const bf16x8 kb11 = *reinterpret_cast<const bf16x8*>(kb + (16 + lr) * ATT_DIM + 32 + g * 8);
        f32x4 t0 = {}; t0 = MFMA16(qa0, kb00, t0); t0 = MFMA16(qa1, kb01, t0);
        f32x4 t1 = {}; t1 = MFMA16(qa0, kb10, t1); t1 = MFMA16(qa1, kb11, t1);
        s[ch][0] = t0; s[ch][1] = t1;
    }

    // ---------------- softmax stats ----------------
    float gm[4];
    #pragma unroll
    for (int j = 0; j < 4; ++j) {
        const float m0_ = fmaxf(fmaxf(s[0][0][j], s[0][1][j]), fmaxf(s[1][0][j], s[1][1][j]));
        const float m1_ = fmaxf(fmaxf(s[2][0][j], s[2][1][j]), fmaxf(s[3][0][j], s[3][1][j]));
        const float m2_ = fmaxf(fmaxf(s[4][0][j], s[4][1][j]), fmaxf(s[5][0][j], s[5][1][j]));
        const float m3_ = fmaxf(fmaxf(s[6][0][j], s[6][1][j]), fmaxf(s[7][0][j], s[7][1][j]));
        float mj = fmaxf(fmaxf(m0_, m1_), fmaxf(m2_, m3_));
        mj = fmaxf(mj, __shfl_xor(mj, 1));
        mj = fmaxf(mj, __shfl_xor(mj, 2));
        mj = fmaxf(mj, __shfl_xor(mj, 4));
        mj = fmaxf(mj, __shfl_xor(mj, 8));
        gm[j] = mj;
    }
    if (lr == 0) {
        #pragma unroll
        for (int j = 0; j < 4; ++j) lds.a.m[w][g * 4 + j] = gm[j];
    }
    __syncthreads();
    #pragma unroll
    for (int j = 0; j < 4; ++j) {
        const int qr = g * 4 + j;
        float mf = lds.a.m[0][qr];
        #pragma unroll
        for (int ww = 1; ww < 8; ++ww) mf = fmaxf(mf, lds.a.m[ww][qr]);
        gm[j] = mf;
    }

    float lsum[4] = {0.f, 0.f, 0.f, 0.f};
    #pragma unroll
    for (int ch = 0; ch < 8; ++ch)
        #pragma unroll
        for (int h = 0; h < 2; ++h)
            #pragma unroll
            for (int j = 0; j < 4; ++j) {
                const float e = __expf(s[ch][h][j] - gm[j]);
                s[ch][h][j] = e;
                lsum[j] += e;
            }
    #pragma unroll
    for (int j = 0; j < 4; ++j) {
        float lj = lsum[j];
        lj += __shfl_xor(lj, 1);
        lj += __shfl_xor(lj, 2);
        lj += __shfl_xor(lj, 4);
        lj += __shfl_xor(lj, 8);
        lsum[j] = lj;
    }
    if (lr == 0) {
        #pragma unroll
        for (int j = 0; j < 4; ++j) lds.a.l[w][g * 4 + j] = lsum[j];
    }
    __syncthreads();
    float invl[4];
    #pragma unroll
    for (int j = 0; j < 4; ++j) {
        const int qr = g * 4 + j;
        float lf = lds.a.l[0][qr];
        #pragma unroll
        for (int ww = 1; ww < 8; ++ww) lf += lds.a.l[ww][qr];
        invl[j] = 1.0f / lf;
    }

    // ---------------- pass B: write probs + PV from registers ----------------
    f32x4 accO[4] = {};
    float* pbase = probs + ((long)b * SEQ + q0) * SEQ;

    #pragma unroll
    for (int ch = 0; ch < 8; ++ch) {
        const int k0 = kbeg + ch * 32;
        #pragma unroll
        for (int h = 0; h < 2; ++h)
            #pragma unroll
            for (int j = 0; j < 4; ++j) {
                const int qr = g * 4 + j;
                const float p = s[ch][h][j] * invl[j];
                pbase[(long)qr * SEQ + k0 + h * 16 + lr] = p;
                lds.a.p[w][qr][h * 16 + lr] = f2bf(p);
            }
        // B-frag for PV: pb[i] = P[q=lr][k-local = 8g+i]
        const bf16x8 pb = *reinterpret_cast<const bf16x8*>(&lds.a.p[w][lr][g * 8]);
        #pragma unroll
        for (int ef = 0; ef < 4; ++ef) {
            const bf16x8 va = *reinterpret_cast<const bf16x8*>(
                vTb + (long)(ef * 16 + lr) * SEQ + k0 + g * 8);
            accO[ef] = MFMA16(va, pb, accO[ef]);
        }
    }

    // ---------------- merge O across waves ----------------
    __syncthreads();   // lds.a.p dead; union now used as lds.o
    #pragma unroll
    for (int ef = 0; ef < 4; ++ef)
        #pragma unroll
        for (int j = 0; j < 4; ++j)
            lds.o[w][ef * 16 + g * 4 + j][lr] = accO[ef][j];
    __syncthreads();

    {
        const int qr = tid >> 5;          // 0..15
        const int e0 = (tid & 31) * 2;    // 0..62
        float o0 = 0.f, o1 = 0.f;
        #pragma unroll
        for (int ww = 0; ww < 8; ++ww) {
            o0 += lds.o[ww][e0][qr];
            o1 += lds.o[ww][e0 + 1][qr];
        }
        float2 o = make_float2(o0, o1);
        *reinterpret_cast<float2*>(att + ((long)b * SEQ + q0 + qr) * ATT_DIM + e0) = o;
    }
}

// ---------------------------------------------------------------------------
extern "C" void kernel_launch(void* const* d_in, const int* in_sizes, int n_in,
                              void* d_out, int out_size, void* d_ws, size_t ws_size,
                              hipStream_t stream)
{
    const float* q  = (const float*)d_in[0];
    const float* k  = (const float*)d_in[1];
    const float* v  = (const float*)d_in[2];
    const float* Wq = (const float*)d_in[3];
    const float* Wk = (const float*)d_in[4];
    const float* Wv = (const float*)d_in[5];

    float* att   = (float*)d_out;                        // [B,S,64]
    float* probs = att + (size_t)BATCH * SEQ * ATT_DIM;  // [B,S,S]

    short* qp  = (short*)d_ws;                    // [B*S,64] bf16 (Wq pre-scaled 1/64)
    short* kp  = qp + (size_t)MROWS * ATT_DIM;    // [B*S,64] bf16
    short* vpT = kp + (size_t)MROWS * ATT_DIM;    // [B][64][S] bf16
    short* Wbf = vpT + (size_t)MROWS * ATT_DIM;   // [3][64][1024] bf16

    wcvt_kernel<<<dim3(96), 256, 0, stream>>>(Wq, Wk, Wv, Wbf);

    proj_mfma_kernel<<<dim3(MROWS / 32, 3), 256, 0, stream>>>(
        q, k, v, Wbf, qp, kp, vpT);

    attn_kernel<<<dim3(SEQ / 16, BATCH), 512, 0, stream>>>(
        qp, kp, vpT, probs, att);
}

// Round 5
// 151.646 us; speedup vs baseline: 2.4589x; 1.1263x over previous
//
#include <hip/hip_runtime.h>
#include <hip/hip_bf16.h>

#define D_MODEL 1024
#define ATT_DIM 64
#define BATCH 8
#define SEQ 2048
#define MROWS (BATCH * SEQ)  // 16384

typedef short bf16x8 __attribute__((ext_vector_type(8)));
typedef float f32x4 __attribute__((ext_vector_type(4)));

#define MFMA16(a, b, c) __builtin_amdgcn_mfma_f32_16x16x32_bf16((a), (b), (c), 0, 0, 0)

__device__ inline short f2bf(float f) {
    union { __hip_bfloat16 h; short s; } u;
    u.h = __float2bfloat16(f);  // RNE
    return u.s;
}

__device__ __forceinline__ void gload_lds16(const float* g, float* l) {
    __builtin_amdgcn_global_load_lds(
        (const __attribute__((address_space(1))) void*)g,
        (__attribute__((address_space(3))) void*)l, 16, 0, 0);
}

// ---------------------------------------------------------------------------
// K0: convert Wq,Wk,Wv fp32 -> bf16 workspace [3][64][1024].
// Wq pre-scaled by 1/64 (exact pow2) so MFMA output == scores.
// ---------------------------------------------------------------------------
__global__ __launch_bounds__(256) void wcvt_kernel(
    const float* __restrict__ Wq, const float* __restrict__ Wk,
    const float* __restrict__ Wv, short* __restrict__ Wbf)
{
    const int idx = blockIdx.x * 256 + threadIdx.x;   // 24576 threads
    const int per = ATT_DIM * D_MODEL;                // 65536
    const int base = idx * 8;
    const int mi = base / per;
    const int off = base - mi * per;
    const float* src = (mi == 0) ? Wq : (mi == 1 ? Wk : Wv);
    const float sc = (mi == 0) ? (1.0f / 64.0f) : 1.0f;
    const float4 a = *reinterpret_cast<const float4*>(src + off);
    const float4 b = *reinterpret_cast<const float4*>(src + off + 4);
    bf16x8 r;
    r[0] = f2bf(a.x * sc); r[1] = f2bf(a.y * sc);
    r[2] = f2bf(a.z * sc); r[3] = f2bf(a.w * sc);
    r[4] = f2bf(b.x * sc); r[5] = f2bf(b.y * sc);
    r[6] = f2bf(b.z * sc); r[7] = f2bf(b.w * sc);
    *reinterpret_cast<bf16x8*>(Wbf + base) = r;
}

// ---------------------------------------------------------------------------
// K1: projections via MFMA with global_load_lds A-streaming.
// Block = 256 thr = 4 waves, 64 rows; K-chunks of 64 fp32, double-buffered
// LDS (2 x 16 KB). A-tile XOR-swizzled (byte ^= (row&7)<<4) on BOTH the
// global source address (stage) and the ds_read address (rule #21).
// W (bf16, L2-resident) read straight from global per fragment.
// V output stored transposed: vpT[b][e][s] bf16.
// ---------------------------------------------------------------------------
__global__ __launch_bounds__(256) void proj_mfma_kernel(
    const float* __restrict__ q, const float* __restrict__ k,
    const float* __restrict__ v, const short* __restrict__ Wbf,
    short* __restrict__ qp, short* __restrict__ kp, short* __restrict__ vpT)
{
    const int mat = blockIdx.y;  // 0:q 1:k 2:v
    const float* x = (mat == 0) ? q : (mat == 1 ? k : v);
    const short* W = Wbf + mat * ATT_DIM * D_MODEL;

    __shared__ float As[2][4096];   // [buf][64 rows x 64 cols], swizzled

    const int tid = threadIdx.x;
    const int w = tid >> 6;
    const int l = tid & 63;
    const int lr = l & 15;
    const int g = l >> 4;

    const int m0 = blockIdx.x * 64;
    const int row = w * 16 + lr;          // this lane's fragment row
    const int xr = (row & 7) << 4;        // read-side XOR (bytes)

    f32x4 acc[4] = {};

    // --- staging: wave w, issue j covers LDS bytes [(w*4+j)*1024, +1024) ---
    // lane l -> lds slot base + l*16 (HW); global row rs, 16B col lr (swizzled)
    #define STAGE(c, buf)                                                      \
        {                                                                      \
            const int kt_ = (c) * 64;                                          \
            _Pragma("unroll")                                                  \
            for (int j = 0; j < 4; ++j) {                                      \
                const int rs = (w * 4 + j) * 4 + g;                            \
                const int scb = (lr * 16) ^ ((rs & 7) << 4);                   \
                gload_lds16(x + (long)(m0 + rs) * D_MODEL + kt_ + (scb >> 2),  \
                            &As[buf][(w * 4 + j) * 256]);                      \
            }                                                                  \
        }

    STAGE(0, 0);
    __syncthreads();

    for (int c = 0; c < 16; ++c) {
        const int buf = c & 1;
        if (c < 15) STAGE(c + 1, buf ^ 1);

        const int kt = c * 64;
        const char* Ab = (const char*)&As[buf][0] + row * 256;
        #pragma unroll
        for (int ks = 0; ks < 2; ++ks) {
            const int b0 = ks * 128 + g * 32;
            const float4 a0 = *reinterpret_cast<const float4*>(Ab + (b0 ^ xr));
            const float4 a1 = *reinterpret_cast<const float4*>(Ab + ((b0 + 16) ^ xr));
            bf16x8 af;
            af[0] = f2bf(a0.x); af[1] = f2bf(a0.y); af[2] = f2bf(a0.z); af[3] = f2bf(a0.w);
            af[4] = f2bf(a1.x); af[5] = f2bf(a1.y); af[6] = f2bf(a1.z); af[7] = f2bf(a1.w);
            #pragma unroll
            for (int ef = 0; ef < 4; ++ef) {
                const bf16x8 wf = *reinterpret_cast<const bf16x8*>(
                    W + (ef * 16 + lr) * D_MODEL + kt + ks * 32 + g * 8);
                acc[ef] = MFMA16(af, wf, acc[ef]);
            }
        }
        __syncthreads();   // drains vmcnt (stage c+1 landed) + read-done sync
    }
    #undef STAGE

    // D layout: row = m0 + w*16 + g*4 + j, col = lr (within 16-col tile ef)
    if (mat < 2) {
        short* out = (mat == 0) ? qp : kp;
        #pragma unroll
        for (int ef = 0; ef < 4; ++ef)
            #pragma unroll
            for (int j = 0; j < 4; ++j)
                out[(long)(m0 + w * 16 + g * 4 + j) * ATT_DIM + ef * 16 + lr] =
                    f2bf(acc[ef][j]);
    } else {
        const int b = m0 / SEQ;                   // 64-row block never straddles batch
        const int s0 = (m0 - b * SEQ) + w * 16;
        #pragma unroll
        for (int ef = 0; ef < 4; ++ef)
            #pragma unroll
            for (int j = 0; j < 4; ++j)
                vpT[((long)b * ATT_DIM + ef * 16 + lr) * SEQ + s0 + g * 4 + j] =
                    f2bf(acc[ef][j]);
    }
}

// ---------------------------------------------------------------------------
// K2: fused scores+softmax+PV with register-resident score panel.
// Block = 512 thr = 8 waves; QBLK=16; wave w owns k-range [w*256,(w+1)*256).
// Pass A: pure QK^T MFMA into s[8][2] (64 VGPR). Softmax: reg tree-max ->
// shfl -> LDS cross-wave max -> exp once per score (in place) -> reg sum ->
// shfl -> LDS cross-wave sum. Pass B: write normalized probs from regs,
// PV via per-wave LDS transpose, MFMA accumulate. O merged across waves in
// LDS (union-overlaid with pass-A/B scratch).
// ---------------------------------------------------------------------------
union AttnSmem {
    struct {
        short p[8][16][40];   // per-wave P transpose tile (80B row, 16B aligned)
        float m[8][16];
        float l[8][16];
    } a;
    float o[8][64][17];       // per-wave O^T for final merge
};

__global__ __launch_bounds__(512) void attn_kernel(
    const short* __restrict__ qp, const short* __restrict__ kp,
    const short* __restrict__ vpT, float* __restrict__ probs,
    float* __restrict__ att)
{
    __shared__ AttnSmem lds;

    const int tid = threadIdx.x;
    const int w = tid >> 6;    // 0..7
    const int l = tid & 63;
    const int lr = l & 15;
    const int g = l >> 4;

    const int b = blockIdx.y;
    const int q0 = blockIdx.x * 16;

    const short* qpb = qp + ((long)b * SEQ + q0) * ATT_DIM;
    const short* kpb = kp + (long)b * SEQ * ATT_DIM;
    const short* vTb = vpT + (long)b * ATT_DIM * SEQ;

    const bf16x8 qa0 = *reinterpret_cast<const bf16x8*>(qpb + lr * ATT_DIM + g * 8);
    const bf16x8 qa1 = *reinterpret_cast<const bf16x8*>(qpb + lr * ATT_DIM + 32 + g * 8);

    const int kbeg = w * 256;

    // ---------------- pass A: QK^T only (fully pipelineable) ----------------
    f32x4 s[8][2];
    #pragma unroll
    for (int ch = 0; ch < 8; ++ch) {
        const short* kb = kpb + (long)(kbeg + ch * 32) * ATT_DIM;
        const bf16x8 kb00 = *reinterpret_cast<const bf16x8*>(kb + lr * ATT_DIM + g * 8);
        const bf16x8 kb01 = *reinterpret_cast<const bf16x8*>(kb + lr * ATT_DIM + 32 + g * 8);
        const bf16x8 kb10 = *reinterpret_cast<const bf16x8*>(kb + (16 + lr) * ATT_DIM + g * 8);
        const bf16x8 kb11 = *reinterpret_cast<const bf16x8*>(kb + (16 + lr) * ATT_DIM + 32 + g * 8);
        f32x4 t0 = {}; t0 = MFMA16(qa0, kb00, t0); t0 = MFMA16(qa1, kb01, t0);
        f32x4 t1 = {}; t1 = MFMA16(qa0, kb10, t1); t1 = MFMA16(qa1, kb11, t1);
        s[ch][0] = t0; s[ch][1] = t1;
    }

    // ---------------- softmax stats ----------------
    float gm[4];
    #pragma unroll
    for (int j = 0; j < 4; ++j) {
        const float m0_ = fmaxf(fmaxf(s[0][0][j], s[0][1][j]), fmaxf(s[1][0][j], s[1][1][j]));
        const float m1_ = fmaxf(fmaxf(s[2][0][j], s[2][1][j]), fmaxf(s[3][0][j], s[3][1][j]));
        const float m2_ = fmaxf(fmaxf(s[4][0][j], s[4][1][j]), fmaxf(s[5][0][j], s[5][1][j]));
        const float m3_ = fmaxf(fmaxf(s[6][0][j], s[6][1][j]), fmaxf(s[7][0][j], s[7][1][j]));
        float mj = fmaxf(fmaxf(m0_, m1_), fmaxf(m2_, m3_));
        mj = fmaxf(mj, __shfl_xor(mj, 1));
        mj = fmaxf(mj, __shfl_xor(mj, 2));
        mj = fmaxf(mj, __shfl_xor(mj, 4));
        mj = fmaxf(mj, __shfl_xor(mj, 8));
        gm[j] = mj;
    }
    if (lr == 0) {
        #pragma unroll
        for (int j = 0; j < 4; ++j) lds.a.m[w][g * 4 + j] = gm[j];
    }
    __syncthreads();
    #pragma unroll
    for (int j = 0; j < 4; ++j) {
        const int qr = g * 4 + j;
        float mf = lds.a.m[0][qr];
        #pragma unroll
        for (int ww = 1; ww < 8; ++ww) mf = fmaxf(mf, lds.a.m[ww][qr]);
        gm[j] = mf;
    }

    float lsum[4] = {0.f, 0.f, 0.f, 0.f};
    #pragma unroll
    for (int ch = 0; ch < 8; ++ch)
        #pragma unroll
        for (int h = 0; h < 2; ++h)
            #pragma unroll
            for (int j = 0; j < 4; ++j) {
                const float e = __expf(s[ch][h][j] - gm[j]);
                s[ch][h][j] = e;
                lsum[j] += e;
            }
    #pragma unroll
    for (int j = 0; j < 4; ++j) {
        float lj = lsum[j];
        lj += __shfl_xor(lj, 1);
        lj += __shfl_xor(lj, 2);
        lj += __shfl_xor(lj, 4);
        lj += __shfl_xor(lj, 8);
        lsum[j] = lj;
    }
    if (lr == 0) {
        #pragma unroll
        for (int j = 0; j < 4; ++j) lds.a.l[w][g * 4 + j] = lsum[j];
    }
    __syncthreads();
    float invl[4];
    #pragma unroll
    for (int j = 0; j < 4; ++j) {
        const int qr = g * 4 + j;
        float lf = lds.a.l[0][qr];
        #pragma unroll
        for (int ww = 1; ww < 8; ++ww) lf += lds.a.l[ww][qr];
        invl[j] = 1.0f / lf;
    }

    // ---------------- pass B: write probs + PV from registers ----------------
    f32x4 accO[4] = {};
    float* pbase = probs + ((long)b * SEQ + q0) * SEQ;

    #pragma unroll
    for (int ch = 0; ch < 8; ++ch) {
        const int k0 = kbeg + ch * 32;
        #pragma unroll
        for (int h = 0; h < 2; ++h)
            #pragma unroll
            for (int j = 0; j < 4; ++j) {
                const int qr = g * 4 + j;
                const float p = s[ch][h][j] * invl[j];
                pbase[(long)qr * SEQ + k0 + h * 16 + lr] = p;
                lds.a.p[w][qr][h * 16 + lr] = f2bf(p);
            }
        // B-frag for PV: pb[i] = P[q=lr][k-local = 8g+i]
        const bf16x8 pb = *reinterpret_cast<const bf16x8*>(&lds.a.p[w][lr][g * 8]);
        #pragma unroll
        for (int ef = 0; ef < 4; ++ef) {
            const bf16x8 va = *reinterpret_cast<const bf16x8*>(
                vTb + (long)(ef * 16 + lr) * SEQ + k0 + g * 8);
            accO[ef] = MFMA16(va, pb, accO[ef]);
        }
    }

    // ---------------- merge O across waves ----------------
    __syncthreads();   // lds.a.p dead; union now used as lds.o
    #pragma unroll
    for (int ef = 0; ef < 4; ++ef)
        #pragma unroll
        for (int j = 0; j < 4; ++j)
            lds.o[w][ef * 16 + g * 4 + j][lr] = accO[ef][j];
    __syncthreads();

    {
        const int qr = tid >> 5;          // 0..15
        const int e0 = (tid & 31) * 2;    // 0..62
        float o0 = 0.f, o1 = 0.f;
        #pragma unroll
        for (int ww = 0; ww < 8; ++ww) {
            o0 += lds.o[ww][e0][qr];
            o1 += lds.o[ww][e0 + 1][qr];
        }
        float2 o = make_float2(o0, o1);
        *reinterpret_cast<float2*>(att + ((long)b * SEQ + q0 + qr) * ATT_DIM + e0) = o;
    }
}

// ---------------------------------------------------------------------------
extern "C" void kernel_launch(void* const* d_in, const int* in_sizes, int n_in,
                              void* d_out, int out_size, void* d_ws, size_t ws_size,
                              hipStream_t stream)
{
    const float* q  = (const float*)d_in[0];
    const float* k  = (const float*)d_in[1];
    const float* v  = (const float*)d_in[2];
    const float* Wq = (const float*)d_in[3];
    const float* Wk = (const float*)d_in[4];
    const float* Wv = (const float*)d_in[5];

    float* att   = (float*)d_out;                        // [B,S,64]
    float* probs = att + (size_t)BATCH * SEQ * ATT_DIM;  // [B,S,S]

    short* qp  = (short*)d_ws;                    // [B*S,64] bf16 (Wq pre-scaled 1/64)
    short* kp  = qp + (size_t)MROWS * ATT_DIM;    // [B*S,64] bf16
    short* vpT = kp + (size_t)MROWS * ATT_DIM;    // [B][64][S] bf16
    short* Wbf = vpT + (size_t)MROWS * ATT_DIM;   // [3][64][1024] bf16

    wcvt_kernel<<<dim3(96), 256, 0, stream>>>(Wq, Wk, Wv, Wbf);

    proj_mfma_kernel<<<dim3(MROWS / 64, 3), 256, 0, stream>>>(
        q, k, v, Wbf, qp, kp, vpT);

    attn_kernel<<<dim3(SEQ / 16, BATCH), 512, 0, stream>>>(
        qp, kp, vpT, probs, att);
}